// Round 1
// baseline (1702.581 us; speedup 1.0000x reference)
//
#include <hip/hip_runtime.h>

typedef unsigned int   u32;
typedef unsigned long long u64;
typedef unsigned int u32x4 __attribute__((ext_vector_type(4)));

// ---------------- helpers ----------------
__device__ __forceinline__ float fast_tanh(float x) {
    x = fminf(fmaxf(x, -15.f), 15.f);
    float e = __expf(2.f * x);
    return __fdividef(e - 1.f, e + 1.f);
}

// coherent 16B load (two tagged u64s) bypassing L1/L2 — used by the LSTM spin
__device__ __forceinline__ u32x4 poll16(const u64* p) {
    u32x4 r;
    asm volatile("global_load_dwordx4 %0, %1, off sc0 sc1\n\ts_waitcnt vmcnt(0)"
                 : "=v"(r) : "v"(p) : "memory");
    return r;
}

// ---------------- workspace layout (bytes, all fp32) ----------------
// xg: 256x3200 (shared by both layers); hist: 2x256x400 u64 (tag-versioned, both layers);
// PQ: 256x3200 (P = cols 0..1599, Q = cols 1600..3199); U: 256x1600.
#define OF_XG   ((size_t)0)
#define OF_H    (OF_XG + 3276800)
#define OF_PQ   (OF_H  + 1638400)
#define OF_U    (OF_PQ + 3276800)

// read 4 consecutive hV elements (t, k..k+3), k%4==0, from tagged hist
__device__ __forceinline__ float4 hist4(const u64* __restrict__ hist, int t, int k) {
    const u64* p = (k < 400) ? hist + (size_t)t * 400 + k
                             : hist + 102400 + (size_t)(255 - t) * 400 + (k - 400);
    ulonglong2 a = *(const ulonglong2*)p;
    ulonglong2 b = *(const ulonglong2*)(p + 2);
    return make_float4(__uint_as_float((u32)a.x), __uint_as_float((u32)a.y),
                       __uint_as_float((u32)b.x), __uint_as_float((u32)b.y));
}

// ---------------- GEMM with A gathered from embeddings (layer-0 xg) ----------------
__global__ __launch_bounds__(256)
void gemm_embed_kernel(const int* __restrict__ words, const int* __restrict__ tags,
                       const float* __restrict__ wemb, const float* __restrict__ temb,
                       const float* __restrict__ B,
                       const float* __restrict__ bias1, const float* __restrict__ bias2,
                       float* __restrict__ C) {
    int t0 = blockIdx.x * 64;
    int n0 = blockIdx.y * 64;
    int tid = threadIdx.x;
    int tx = tid & 15, ty = tid >> 4;
    int lr = tid >> 2, lk = (tid & 3) * 4;
    __shared__ float As[16][68];
    __shared__ float Bs[16][68];
    float acc[4][4] = {};

    int t = t0 + lr;
    const float* arow0 = wemb + (size_t)words[t] * 300;
    const float* arow1 = temb + (size_t)tags[t] * 100 - 300;   // indexed by k directly

    for (int k0 = 0; k0 < 400; k0 += 16) {
        int k = k0 + lk;   // 300 % 4 == 0, so each float4 stays in one table
        float4 av = (k < 300) ? *(const float4*)(arow0 + k) : *(const float4*)(arow1 + k);
        float4 bv = *(const float4*)(B + (size_t)(n0 + lr) * 400 + k);
        __syncthreads();
        As[lk + 0][lr] = av.x; As[lk + 1][lr] = av.y; As[lk + 2][lr] = av.z; As[lk + 3][lr] = av.w;
        Bs[lk + 0][lr] = bv.x; Bs[lk + 1][lr] = bv.y; Bs[lk + 2][lr] = bv.z; Bs[lk + 3][lr] = bv.w;
        __syncthreads();
        #pragma unroll
        for (int kk = 0; kk < 16; ++kk) {
            float4 a4 = *(const float4*)&As[kk][ty * 4];
            float4 b4 = *(const float4*)&Bs[kk][tx * 4];
            acc[0][0] += a4.x * b4.x; acc[0][1] += a4.x * b4.y; acc[0][2] += a4.x * b4.z; acc[0][3] += a4.x * b4.w;
            acc[1][0] += a4.y * b4.x; acc[1][1] += a4.y * b4.y; acc[1][2] += a4.y * b4.z; acc[1][3] += a4.y * b4.w;
            acc[2][0] += a4.z * b4.x; acc[2][1] += a4.z * b4.y; acc[2][2] += a4.z * b4.z; acc[2][3] += a4.z * b4.w;
            acc[3][0] += a4.w * b4.x; acc[3][1] += a4.w * b4.y; acc[3][2] += a4.w * b4.z; acc[3][3] += a4.w * b4.w;
        }
    }
    float bs[4];
    #pragma unroll
    for (int j = 0; j < 4; ++j) {
        int n = n0 + tx * 4 + j;
        bs[j] = bias1[n] + bias2[n];
    }
    #pragma unroll
    for (int i = 0; i < 4; ++i) {
        int tr = t0 + ty * 4 + i;
        float4 o;
        o.x = acc[i][0] + bs[0]; o.y = acc[i][1] + bs[1];
        o.z = acc[i][2] + bs[2]; o.w = acc[i][3] + bs[3];
        *(float4*)(C + (size_t)tr * 3200 + n0 + tx * 4) = o;
    }
}

// ---------------- GEMM with A read from tagged hist (hV on the fly) ----------------
__global__ __launch_bounds__(256)
void gemm_hist_kernel(const u64* __restrict__ hist, const int* __restrict__ arcs,
                      const float* __restrict__ B, int ldb, int boff,
                      const float* __restrict__ bias1, const float* __restrict__ bias2,
                      float* __restrict__ C, int ldc, int K, int act) {
    int t0 = blockIdx.x * 64;
    int n0 = blockIdx.y * 64;
    int tid = threadIdx.x;
    int tx = tid & 15, ty = tid >> 4;
    int lr = tid >> 2, lk = (tid & 3) * 4;
    __shared__ float As[16][68];
    __shared__ float Bs[16][68];
    float acc[4][4] = {};

    int t = t0 + lr;
    int tind = t;
    if (arcs) {
        int h = arcs[1 + t];
        tind = min(max(h - 1, 0), 255);
    }

    for (int k0 = 0; k0 < K; k0 += 16) {
        int k = k0 + lk;
        int tt = (k < 800) ? t : tind;
        int kk2 = (k < 800) ? k : k - 800;
        float4 av = hist4(hist, tt, kk2);
        float4 bv = *(const float4*)(B + (size_t)(n0 + lr) * ldb + boff + k0 + lk);
        __syncthreads();
        As[lk + 0][lr] = av.x; As[lk + 1][lr] = av.y; As[lk + 2][lr] = av.z; As[lk + 3][lr] = av.w;
        Bs[lk + 0][lr] = bv.x; Bs[lk + 1][lr] = bv.y; Bs[lk + 2][lr] = bv.z; Bs[lk + 3][lr] = bv.w;
        __syncthreads();
        #pragma unroll
        for (int kk = 0; kk < 16; ++kk) {
            float4 a4 = *(const float4*)&As[kk][ty * 4];
            float4 b4 = *(const float4*)&Bs[kk][tx * 4];
            acc[0][0] += a4.x * b4.x; acc[0][1] += a4.x * b4.y; acc[0][2] += a4.x * b4.z; acc[0][3] += a4.x * b4.w;
            acc[1][0] += a4.y * b4.x; acc[1][1] += a4.y * b4.y; acc[1][2] += a4.y * b4.z; acc[1][3] += a4.y * b4.w;
            acc[2][0] += a4.z * b4.x; acc[2][1] += a4.z * b4.y; acc[2][2] += a4.z * b4.z; acc[2][3] += a4.z * b4.w;
            acc[3][0] += a4.w * b4.x; acc[3][1] += a4.w * b4.y; acc[3][2] += a4.w * b4.z; acc[3][3] += a4.w * b4.w;
        }
    }
    float bs[4];
    #pragma unroll
    for (int j = 0; j < 4; ++j) {
        int n = n0 + tx * 4 + j;
        float b = 0.f;
        if (bias1) b += bias1[n];
        if (bias2) b += bias2[n];
        bs[j] = b;
    }
    #pragma unroll
    for (int i = 0; i < 4; ++i) {
        int tr = t0 + ty * 4 + i;
        float4 o;
        o.x = acc[i][0] + bs[0]; o.y = acc[i][1] + bs[1];
        o.z = acc[i][2] + bs[2]; o.w = acc[i][3] + bs[3];
        if (act) { o.x = fast_tanh(o.x); o.y = fast_tanh(o.y); o.z = fast_tanh(o.z); o.w = fast_tanh(o.w); }
        *(float4*)(C + (size_t)tr * ldc + n0 + tx * 4) = o;
    }
}

// ---------------- fused P|Q GEMM from hist ----------------
__global__ __launch_bounds__(256)
void gemm_pq_kernel(const u64* __restrict__ hist, const float* __restrict__ Wa1,
                    const float* __restrict__ ba1, float* __restrict__ PQ) {
    int t0 = blockIdx.x * 64;
    int n0 = blockIdx.y * 64;
    int tid = threadIdx.x;
    int tx = tid & 15, ty = tid >> 4;
    int lr = tid >> 2, lk = (tid & 3) * 4;
    __shared__ float As[16][68];
    __shared__ float Bs[16][68];
    float acc[4][4] = {};

    int t = t0 + lr;
    int nn = n0 + lr;                        // uniform per thread: which B row + k-offset
    const float* brow = (nn < 1600) ? Wa1 + (size_t)nn * 1600
                                    : Wa1 + (size_t)(nn - 1600) * 1600 + 800;

    for (int k0 = 0; k0 < 800; k0 += 16) {
        float4 av = hist4(hist, t, k0 + lk);
        float4 bv = *(const float4*)(brow + k0 + lk);
        __syncthreads();
        As[lk + 0][lr] = av.x; As[lk + 1][lr] = av.y; As[lk + 2][lr] = av.z; As[lk + 3][lr] = av.w;
        Bs[lk + 0][lr] = bv.x; Bs[lk + 1][lr] = bv.y; Bs[lk + 2][lr] = bv.z; Bs[lk + 3][lr] = bv.w;
        __syncthreads();
        #pragma unroll
        for (int kk = 0; kk < 16; ++kk) {
            float4 a4 = *(const float4*)&As[kk][ty * 4];
            float4 b4 = *(const float4*)&Bs[kk][tx * 4];
            acc[0][0] += a4.x * b4.x; acc[0][1] += a4.x * b4.y; acc[0][2] += a4.x * b4.z; acc[0][3] += a4.x * b4.w;
            acc[1][0] += a4.y * b4.x; acc[1][1] += a4.y * b4.y; acc[1][2] += a4.y * b4.z; acc[1][3] += a4.y * b4.w;
            acc[2][0] += a4.z * b4.x; acc[2][1] += a4.z * b4.y; acc[2][2] += a4.z * b4.z; acc[2][3] += a4.z * b4.w;
            acc[3][0] += a4.w * b4.x; acc[3][1] += a4.w * b4.y; acc[3][2] += a4.w * b4.z; acc[3][3] += a4.w * b4.w;
        }
    }
    float bs[4];
    #pragma unroll
    for (int j = 0; j < 4; ++j) {
        int n = n0 + tx * 4 + j;
        bs[j] = (n < 1600) ? ba1[n] : 0.f;
    }
    #pragma unroll
    for (int i = 0; i < 4; ++i) {
        int tr = t0 + ty * 4 + i;
        float4 o;
        o.x = acc[i][0] + bs[0]; o.y = acc[i][1] + bs[1];
        o.z = acc[i][2] + bs[2]; o.w = acc[i][3] + bs[3];
        *(float4*)(PQ + (size_t)tr * 3200 + n0 + tx * 4) = o;
    }
}

// ---------------- persistent distributed LSTM ----------------
// R5: 25 blocks/direction x 16 hidden units (was 50x8); each lane owns 2 gate-rows;
// spin uses paired 16B coherent polls (threads 0..199 cover all 400 tagged u64s).
#define LSTM_G 25
__global__ __launch_bounds__(256)
void lstm_kernel(const float* __restrict__ Whh,   // (2,1600,400)
                 const float* __restrict__ h0,    // (4,400)
                 const float* __restrict__ c0,    // (4,400)
                 int hc_base,
                 const float* __restrict__ xg,    // (256,3200): [t][d*1600 + gaterow]
                 u64* __restrict__ hist,          // (2,256,400)
                 u32 tag_base) {
    const int T = 256;
    int bid = blockIdx.x;
    int d  = bid / LSTM_G;
    int wg = bid % LSTM_G;
    int a16 = wg * 16;
    int tid = threadIdx.x;
    int w = tid >> 6, lane = tid & 63;
    int c = lane & 7, r = lane >> 3;
    int gate = r >> 1, half = r & 1;
    int ub  = a16 + 4 * w + half * 2;       // base unit of this lane's pair
    int grA = gate * 400 + ub;              // gate-row for unit ub
    // gate-row for unit ub+1 is grA+1

    __shared__ float hbuf[2][416];

    float4 wvA[13], wvB[13];
    const float* rowA = Whh + (size_t)d * 640000 + (size_t)grA * 400;
    const float* rowB = rowA + 400;
    #pragma unroll
    for (int i = 0; i < 13; ++i) {
        int k = 4 * (c + 8 * i);
        if (k + 3 < 400) { wvA[i] = *(const float4*)(rowA + k); wvB[i] = *(const float4*)(rowB + k); }
        else             { wvA[i] = make_float4(0.f,0.f,0.f,0.f); wvB[i] = make_float4(0.f,0.f,0.f,0.f); }
    }
    if (tid < 16) { hbuf[0][400 + tid] = 0.f; hbuf[1][400 + tid] = 0.f; }

    float cA = 0.f, cB = 0.f;
    if (c == 0 && gate == 0) {
        cA = c0[(hc_base + d) * 400 + ub];
        cB = c0[(hc_base + d) * 400 + ub + 1];
    }

    u64* hst = hist + (size_t)d * 102400;

    for (int t = 0; t < T; ++t) {
        int xt = d ? (T - 1 - t) : t;
        float2 xg2 = *(const float2*)(xg + (size_t)xt * 3200 + d * 1600 + grA);
        float* hb = hbuf[t & 1];

        if (t == 0) {
            hb[tid] = h0[(hc_base + d) * 400 + tid];
            if (tid < 144) hb[tid + 256] = h0[(hc_base + d) * 400 + tid + 256];
        } else if (tid < 200) {
            const u64* src = hst + (size_t)(t - 1) * 400 + 2 * tid;
            u32 want = tag_base + (u32)t;
            for (;;) {
                u32x4 v = poll16(src);
                if (v.y == want && v.w == want) {
                    hb[2 * tid]     = __uint_as_float(v.x);
                    hb[2 * tid + 1] = __uint_as_float(v.z);
                    break;
                }
            }
        }
        __syncthreads();

        const float4* h4 = (const float4*)hb;
        float a0 = 0.f, a1 = 0.f, b0 = 0.f, b1 = 0.f;
        #pragma unroll
        for (int i = 0; i < 13; ++i) {
            float4 hv = h4[c + 8 * i];
            float4 wa = wvA[i], wb = wvB[i];
            if (i & 1) {
                a1 += wa.x * hv.x + wa.y * hv.y + wa.z * hv.z + wa.w * hv.w;
                b1 += wb.x * hv.x + wb.y * hv.y + wb.z * hv.z + wb.w * hv.w;
            } else {
                a0 += wa.x * hv.x + wa.y * hv.y + wa.z * hv.z + wa.w * hv.w;
                b0 += wb.x * hv.x + wb.y * hv.y + wb.z * hv.z + wb.w * hv.w;
            }
        }
        float sA = a0 + a1, sB = b0 + b1;
        sA += __shfl_down(sA, 4); sB += __shfl_down(sB, 4);
        sA += __shfl_down(sA, 2); sB += __shfl_down(sB, 2);
        sA += __shfl_down(sA, 1); sB += __shfl_down(sB, 1);

        float vA = 0.f, vB = 0.f;
        if (c == 0) {
            float totA = sA + xg2.x;
            float totB = sB + xg2.y;
            float argA = (gate == 2) ? 2.f * totA : -totA;
            float argB = (gate == 2) ? 2.f * totB : -totB;
            argA = fminf(fmaxf(argA, -60.f), 60.f);
            argB = fminf(fmaxf(argB, -60.f), 60.f);
            float eA = __expf(argA), eB = __expf(argB);
            if (gate == 2) {
                vA = (eA - 1.f) * __frcp_rn(eA + 1.f);
                vB = (eB - 1.f) * __frcp_rn(eB + 1.f);
            } else {
                vA = __frcp_rn(1.f + eA);
                vB = __frcp_rn(1.f + eB);
            }
        }
        float fA = __shfl(vA, lane + 16);
        float gA = __shfl(vA, lane + 32);
        float oA = __shfl(vA, lane + 48);
        float fB = __shfl(vB, lane + 16);
        float gB = __shfl(vB, lane + 32);
        float oB = __shfl(vB, lane + 48);
        if (c == 0 && gate == 0) {   // lanes 0 and 8 of each wave
            cA = fA * cA + vA * gA;
            cB = fB * cB + vB * gB;
            float ecA = __expf(fminf(fmaxf(2.f * cA, -60.f), 60.f));
            float ecB = __expf(fminf(fmaxf(2.f * cB, -60.f), 60.f));
            float hA = oA * ((ecA - 1.f) * __frcp_rn(ecA + 1.f));
            float hB = oB * ((ecB - 1.f) * __frcp_rn(ecB + 1.f));
            u64 tagw = ((u64)(tag_base + t + 1)) << 32;
            u64 pkA = tagw | (u64)__float_as_uint(hA);
            u64 pkB = tagw | (u64)__float_as_uint(hB);
            __hip_atomic_store(&hst[(size_t)t * 400 + ub],     pkA,
                               __ATOMIC_RELAXED, __HIP_MEMORY_SCOPE_AGENT);
            __hip_atomic_store(&hst[(size_t)t * 400 + ub + 1], pkB,
                               __ATOMIC_RELAXED, __HIP_MEMORY_SCOPE_AGENT);
        }
    }
}

// ---------------- arc pairwise scorer (+ borders, folded in) ----------------
__global__ __launch_bounds__(256)
void arc_kernel(const float* __restrict__ PQ,
                const float* __restrict__ Wa2, const float* __restrict__ ba2,
                float* __restrict__ out) {
    int i0 = blockIdx.x * 16, j0 = blockIdx.y * 16;
    int tid = threadIdx.x;
    int ii = tid >> 4, jj = tid & 15;
    __shared__ float Pt[16][65], Qt[16][65];
    __shared__ float W2f[1600];

    if (i0 == 0 && j0 == 0) {   // borders: row 0 (with [0,0]=1) and col 0
        if (tid < 257) out[tid] = (tid == 0) ? 1.0f : 0.0f;
        out[(size_t)(tid + 1) * 257] = 0.0f;
        if (tid == 0) out[0] = 1.0f;
    }
    for (int m = tid; m < 1600; m += 256) W2f[m] = Wa2[m];
    __syncthreads();

    float acc = 0.f;
    int mm = tid & 63, r4 = tid >> 6;
    for (int m0 = 0; m0 < 1600; m0 += 64) {
        #pragma unroll
        for (int rr = r4; rr < 16; rr += 4) {
            Pt[rr][mm] = PQ[(size_t)(i0 + rr) * 3200 + m0 + mm];
            Qt[rr][mm] = PQ[(size_t)(j0 + rr) * 3200 + 1600 + m0 + mm];
        }
        __syncthreads();
        #pragma unroll 8
        for (int m = 0; m < 64; ++m) {
            float s = Pt[ii][m] + Qt[jj][m];
            acc += W2f[m0 + m] * fast_tanh(s);
        }
        __syncthreads();
    }
    float raw = acc + ba2[0];
    int gi = i0 + ii, gj = j0 + jj;
    if (gi == gj) raw = 0.f;
    out[(size_t)(gi + 1) * 257 + (gj + 1)] = raw;
}

// ---------------- label output ----------------
__global__ __launch_bounds__(256)
void label_out_kernel(const float* __restrict__ U, const float* __restrict__ Wl2,
                      const float* __restrict__ bl2, const int* __restrict__ arcs,
                      float* __restrict__ out) {
    int t = blockIdx.x;
    __shared__ float u_l[1600];
    __shared__ float part[4][64];
    for (int m = threadIdx.x; m < 1600; m += 256) u_l[m] = U[(size_t)t * 1600 + m];
    __syncthreads();
    int tid = threadIdx.x;
    int n = tid & 63, p = tid >> 6;
    float acc = 0.f;
    if (n < 40) {
        const float4* wr4 = (const float4*)(Wl2 + (size_t)n * 1600 + p * 400);
        const float*  ub  = u_l + p * 400;
        for (int m = 0; m < 100; ++m) {
            float4 w = wr4[m];
            acc += ub[4*m] * w.x + ub[4*m+1] * w.y + ub[4*m+2] * w.z + ub[4*m+3] * w.w;
        }
    }
    part[p][n] = acc;
    __syncthreads();
    if (tid < 40) {
        float v = part[0][tid] + part[1][tid] + part[2][tid] + part[3][tid] + bl2[tid];
        if (arcs[1 + t] == 0) v = 0.f;
        out[(size_t)t * 40 + tid] = v;
    }
}

// ---------------- launch ----------------
extern "C" void kernel_launch(void* const* d_in, const int* in_sizes, int n_in,
                              void* d_out, int out_size, void* d_ws, size_t ws_size,
                              hipStream_t stream) {
    const int*   words = (const int*)d_in[0];
    const int*   tags  = (const int*)d_in[1];
    const int*   arcs  = (const int*)d_in[2];
    const float* h0    = (const float*)d_in[3];
    const float* c0    = (const float*)d_in[4];
    const float* wemb  = (const float*)d_in[5];
    const float* temb  = (const float*)d_in[6];
    const float* Wih0  = (const float*)d_in[7];
    const float* Whh0  = (const float*)d_in[8];
    const float* bih0  = (const float*)d_in[9];
    const float* bhh0  = (const float*)d_in[10];
    const float* Wih1  = (const float*)d_in[11];
    const float* Whh1  = (const float*)d_in[12];
    const float* bih1  = (const float*)d_in[13];
    const float* bhh1  = (const float*)d_in[14];
    const float* Wa1   = (const float*)d_in[15];
    const float* ba1   = (const float*)d_in[16];
    const float* Wa2   = (const float*)d_in[17];
    const float* ba2   = (const float*)d_in[18];
    const float* Wl1   = (const float*)d_in[19];
    const float* bl1   = (const float*)d_in[20];
    const float* Wl2   = (const float*)d_in[21];
    const float* bl2   = (const float*)d_in[22];
    float* out = (float*)d_out;

    char* ws = (char*)d_ws;
    float* xg   = (float*)(ws + OF_XG);
    u64*   hist = (u64*)  (ws + OF_H);
    float* PQ   = (float*)(ws + OF_PQ);
    float* U    = (float*)(ws + OF_U);

    gemm_embed_kernel<<<dim3(4, 50), 256, 0, stream>>>(words, tags, wemb, temb, Wih0, bih0, bhh0, xg);
    lstm_kernel<<<2 * LSTM_G, 256, 0, stream>>>(Whh0, h0, c0, 0, xg, hist, 0u);
    gemm_hist_kernel<<<dim3(4, 50), 256, 0, stream>>>(hist, nullptr, Wih1, 800, 0, bih1, bhh1, xg, 3200, 800, 0);
    lstm_kernel<<<2 * LSTM_G, 256, 0, stream>>>(Whh1, h0, c0, 2, xg, hist, 256u);
    gemm_pq_kernel<<<dim3(4, 50), 256, 0, stream>>>(hist, Wa1, ba1, PQ);
    arc_kernel<<<dim3(16, 16), 256, 0, stream>>>(PQ, Wa2, ba2, out);
    gemm_hist_kernel<<<dim3(4, 25), 256, 0, stream>>>(hist, arcs, Wl1, 1600, 0, bl1, nullptr, U, 1600, 1600, 1);
    label_out_kernel<<<256, 256, 0, stream>>>(U, Wl2, bl2, arcs, out + 66049);
}

// Round 2
// 1209.679 us; speedup vs baseline: 1.4075x; 1.4075x over previous
//
#include <hip/hip_runtime.h>

typedef unsigned int   u32;
typedef unsigned long long u64;

// ---------------- helpers ----------------
__device__ __forceinline__ float fast_tanh(float x) {
    x = fminf(fmaxf(x, -15.f), 15.f);
    float e = __expf(2.f * x);
    return __fdividef(e - 1.f, e + 1.f);
}

// ---------------- workspace layout (bytes, all fp32) ----------------
// xg: 256x3200 (shared by both layers); hist: 2x256x400 u64 (tag-versioned, both layers);
// PQ: 256x3200 (P = cols 0..1599, Q = cols 1600..3199); U: 256x1600.
#define OF_XG   ((size_t)0)
#define OF_H    (OF_XG + 3276800)
#define OF_PQ   (OF_H  + 1638400)
#define OF_U    (OF_PQ + 3276800)

// read 4 consecutive hV elements (t, k..k+3), k%4==0, from tagged hist
__device__ __forceinline__ float4 hist4(const u64* __restrict__ hist, int t, int k) {
    const u64* p = (k < 400) ? hist + (size_t)t * 400 + k
                             : hist + 102400 + (size_t)(255 - t) * 400 + (k - 400);
    ulonglong2 a = *(const ulonglong2*)p;
    ulonglong2 b = *(const ulonglong2*)(p + 2);
    return make_float4(__uint_as_float((u32)a.x), __uint_as_float((u32)a.y),
                       __uint_as_float((u32)b.x), __uint_as_float((u32)b.y));
}

// ---------------- GEMM with A gathered from embeddings (layer-0 xg) ----------------
__global__ __launch_bounds__(256)
void gemm_embed_kernel(const int* __restrict__ words, const int* __restrict__ tags,
                       const float* __restrict__ wemb, const float* __restrict__ temb,
                       const float* __restrict__ B,
                       const float* __restrict__ bias1, const float* __restrict__ bias2,
                       float* __restrict__ C) {
    int t0 = blockIdx.x * 64;
    int n0 = blockIdx.y * 64;
    int tid = threadIdx.x;
    int tx = tid & 15, ty = tid >> 4;
    int lr = tid >> 2, lk = (tid & 3) * 4;
    __shared__ float As[16][68];
    __shared__ float Bs[16][68];
    float acc[4][4] = {};

    int t = t0 + lr;
    const float* arow0 = wemb + (size_t)words[t] * 300;
    const float* arow1 = temb + (size_t)tags[t] * 100 - 300;   // indexed by k directly

    for (int k0 = 0; k0 < 400; k0 += 16) {
        int k = k0 + lk;   // 300 % 4 == 0, so each float4 stays in one table
        float4 av = (k < 300) ? *(const float4*)(arow0 + k) : *(const float4*)(arow1 + k);
        float4 bv = *(const float4*)(B + (size_t)(n0 + lr) * 400 + k);
        __syncthreads();
        As[lk + 0][lr] = av.x; As[lk + 1][lr] = av.y; As[lk + 2][lr] = av.z; As[lk + 3][lr] = av.w;
        Bs[lk + 0][lr] = bv.x; Bs[lk + 1][lr] = bv.y; Bs[lk + 2][lr] = bv.z; Bs[lk + 3][lr] = bv.w;
        __syncthreads();
        #pragma unroll
        for (int kk = 0; kk < 16; ++kk) {
            float4 a4 = *(const float4*)&As[kk][ty * 4];
            float4 b4 = *(const float4*)&Bs[kk][tx * 4];
            acc[0][0] += a4.x * b4.x; acc[0][1] += a4.x * b4.y; acc[0][2] += a4.x * b4.z; acc[0][3] += a4.x * b4.w;
            acc[1][0] += a4.y * b4.x; acc[1][1] += a4.y * b4.y; acc[1][2] += a4.y * b4.z; acc[1][3] += a4.y * b4.w;
            acc[2][0] += a4.z * b4.x; acc[2][1] += a4.z * b4.y; acc[2][2] += a4.z * b4.z; acc[2][3] += a4.z * b4.w;
            acc[3][0] += a4.w * b4.x; acc[3][1] += a4.w * b4.y; acc[3][2] += a4.w * b4.z; acc[3][3] += a4.w * b4.w;
        }
    }
    float bs[4];
    #pragma unroll
    for (int j = 0; j < 4; ++j) {
        int n = n0 + tx * 4 + j;
        bs[j] = bias1[n] + bias2[n];
    }
    #pragma unroll
    for (int i = 0; i < 4; ++i) {
        int tr = t0 + ty * 4 + i;
        float4 o;
        o.x = acc[i][0] + bs[0]; o.y = acc[i][1] + bs[1];
        o.z = acc[i][2] + bs[2]; o.w = acc[i][3] + bs[3];
        *(float4*)(C + (size_t)tr * 3200 + n0 + tx * 4) = o;
    }
}

// ---------------- GEMM with A read from tagged hist (used for layer-1 xg) ----------------
__global__ __launch_bounds__(256)
void gemm_hist_kernel(const u64* __restrict__ hist, const int* __restrict__ arcs,
                      const float* __restrict__ B, int ldb, int boff,
                      const float* __restrict__ bias1, const float* __restrict__ bias2,
                      float* __restrict__ C, int ldc, int K, int act) {
    int t0 = blockIdx.x * 64;
    int n0 = blockIdx.y * 64;
    int tid = threadIdx.x;
    int tx = tid & 15, ty = tid >> 4;
    int lr = tid >> 2, lk = (tid & 3) * 4;
    __shared__ float As[16][68];
    __shared__ float Bs[16][68];
    float acc[4][4] = {};

    int t = t0 + lr;
    int tind = t;
    if (arcs) {
        int h = arcs[1 + t];
        tind = min(max(h - 1, 0), 255);
    }

    for (int k0 = 0; k0 < K; k0 += 16) {
        int k = k0 + lk;
        int tt = (k < 800) ? t : tind;
        int kk2 = (k < 800) ? k : k - 800;
        float4 av = hist4(hist, tt, kk2);
        float4 bv = *(const float4*)(B + (size_t)(n0 + lr) * ldb + boff + k0 + lk);
        __syncthreads();
        As[lk + 0][lr] = av.x; As[lk + 1][lr] = av.y; As[lk + 2][lr] = av.z; As[lk + 3][lr] = av.w;
        Bs[lk + 0][lr] = bv.x; Bs[lk + 1][lr] = bv.y; Bs[lk + 2][lr] = bv.z; Bs[lk + 3][lr] = bv.w;
        __syncthreads();
        #pragma unroll
        for (int kk = 0; kk < 16; ++kk) {
            float4 a4 = *(const float4*)&As[kk][ty * 4];
            float4 b4 = *(const float4*)&Bs[kk][tx * 4];
            acc[0][0] += a4.x * b4.x; acc[0][1] += a4.x * b4.y; acc[0][2] += a4.x * b4.z; acc[0][3] += a4.x * b4.w;
            acc[1][0] += a4.y * b4.x; acc[1][1] += a4.y * b4.y; acc[1][2] += a4.y * b4.z; acc[1][3] += a4.y * b4.w;
            acc[2][0] += a4.z * b4.x; acc[2][1] += a4.z * b4.y; acc[2][2] += a4.z * b4.z; acc[2][3] += a4.z * b4.w;
            acc[3][0] += a4.w * b4.x; acc[3][1] += a4.w * b4.y; acc[3][2] += a4.w * b4.z; acc[3][3] += a4.w * b4.w;
        }
    }
    float bs[4];
    #pragma unroll
    for (int j = 0; j < 4; ++j) {
        int n = n0 + tx * 4 + j;
        float b = 0.f;
        if (bias1) b += bias1[n];
        if (bias2) b += bias2[n];
        bs[j] = b;
    }
    #pragma unroll
    for (int i = 0; i < 4; ++i) {
        int tr = t0 + ty * 4 + i;
        float4 o;
        o.x = acc[i][0] + bs[0]; o.y = acc[i][1] + bs[1];
        o.z = acc[i][2] + bs[2]; o.w = acc[i][3] + bs[3];
        if (act) { o.x = fast_tanh(o.x); o.y = fast_tanh(o.y); o.z = fast_tanh(o.z); o.w = fast_tanh(o.w); }
        *(float4*)(C + (size_t)tr * ldc + n0 + tx * 4) = o;
    }
}

// ---------------- merged PQ + U GEMM (concurrent, U tiles dispatched first) ----------------
// grid (4, 75): blockIdx.y <  25 -> U tile  (n0 = by*64, K=1600, C=U, tanh, bias bl1)
//               blockIdx.y >= 25 -> PQ tile (n0 = (by-25)*64, K=800, C=PQ)
// U tiles are ~2x longer per block, so they go first in dispatch order: all 100 start at
// t=0 and the 200 PQ tiles pack around them -> makespan ~ t_U instead of t_PQ + t_U.
__global__ __launch_bounds__(256)
void pq_u_kernel(const u64* __restrict__ hist, const int* __restrict__ arcs,
                 const float* __restrict__ Wa1, const float* __restrict__ ba1,
                 const float* __restrict__ Wl1, const float* __restrict__ bl1,
                 float* __restrict__ PQ, float* __restrict__ U) {
    int t0 = blockIdx.x * 64;
    int by = blockIdx.y;
    int tid = threadIdx.x;
    int tx = tid & 15, ty = tid >> 4;
    int lr = tid >> 2, lk = (tid & 3) * 4;
    __shared__ float As[16][68];
    __shared__ float Bs[16][68];
    float acc[4][4] = {};
    int t = t0 + lr;

    if (by < 25) {
        // ---- U path: U[t][n] = tanh( [hV[t], hV[head(t)]] @ Wl1[n] + bl1[n] ) ----
        int n0 = by * 64;
        int h = arcs[1 + t];
        int tind = min(max(h - 1, 0), 255);
        for (int k0 = 0; k0 < 1600; k0 += 16) {
            int k = k0 + lk;
            int tt  = (k < 800) ? t : tind;
            int kk2 = (k < 800) ? k : k - 800;
            float4 av = hist4(hist, tt, kk2);
            float4 bv = *(const float4*)(Wl1 + (size_t)(n0 + lr) * 1600 + k);
            __syncthreads();
            As[lk + 0][lr] = av.x; As[lk + 1][lr] = av.y; As[lk + 2][lr] = av.z; As[lk + 3][lr] = av.w;
            Bs[lk + 0][lr] = bv.x; Bs[lk + 1][lr] = bv.y; Bs[lk + 2][lr] = bv.z; Bs[lk + 3][lr] = bv.w;
            __syncthreads();
            #pragma unroll
            for (int kk = 0; kk < 16; ++kk) {
                float4 a4 = *(const float4*)&As[kk][ty * 4];
                float4 b4 = *(const float4*)&Bs[kk][tx * 4];
                acc[0][0] += a4.x * b4.x; acc[0][1] += a4.x * b4.y; acc[0][2] += a4.x * b4.z; acc[0][3] += a4.x * b4.w;
                acc[1][0] += a4.y * b4.x; acc[1][1] += a4.y * b4.y; acc[1][2] += a4.y * b4.z; acc[1][3] += a4.y * b4.w;
                acc[2][0] += a4.z * b4.x; acc[2][1] += a4.z * b4.y; acc[2][2] += a4.z * b4.z; acc[2][3] += a4.z * b4.w;
                acc[3][0] += a4.w * b4.x; acc[3][1] += a4.w * b4.y; acc[3][2] += a4.w * b4.z; acc[3][3] += a4.w * b4.w;
            }
        }
        float bs[4];
        #pragma unroll
        for (int j = 0; j < 4; ++j) bs[j] = bl1[n0 + tx * 4 + j];
        #pragma unroll
        for (int i = 0; i < 4; ++i) {
            int tr = t0 + ty * 4 + i;
            float4 o;
            o.x = fast_tanh(acc[i][0] + bs[0]); o.y = fast_tanh(acc[i][1] + bs[1]);
            o.z = fast_tanh(acc[i][2] + bs[2]); o.w = fast_tanh(acc[i][3] + bs[3]);
            *(float4*)(U + (size_t)tr * 1600 + n0 + tx * 4) = o;
        }
    } else {
        // ---- PQ path ----
        int n0 = (by - 25) * 64;
        int nn = n0 + lr;                        // uniform per thread: which B row + k-offset
        const float* brow = (nn < 1600) ? Wa1 + (size_t)nn * 1600
                                        : Wa1 + (size_t)(nn - 1600) * 1600 + 800;
        for (int k0 = 0; k0 < 800; k0 += 16) {
            float4 av = hist4(hist, t, k0 + lk);
            float4 bv = *(const float4*)(brow + k0 + lk);
            __syncthreads();
            As[lk + 0][lr] = av.x; As[lk + 1][lr] = av.y; As[lk + 2][lr] = av.z; As[lk + 3][lr] = av.w;
            Bs[lk + 0][lr] = bv.x; Bs[lk + 1][lr] = bv.y; Bs[lk + 2][lr] = bv.z; Bs[lk + 3][lr] = bv.w;
            __syncthreads();
            #pragma unroll
            for (int kk = 0; kk < 16; ++kk) {
                float4 a4 = *(const float4*)&As[kk][ty * 4];
                float4 b4 = *(const float4*)&Bs[kk][tx * 4];
                acc[0][0] += a4.x * b4.x; acc[0][1] += a4.x * b4.y; acc[0][2] += a4.x * b4.z; acc[0][3] += a4.x * b4.w;
                acc[1][0] += a4.y * b4.x; acc[1][1] += a4.y * b4.y; acc[1][2] += a4.y * b4.z; acc[1][3] += a4.y * b4.w;
                acc[2][0] += a4.z * b4.x; acc[2][1] += a4.z * b4.y; acc[2][2] += a4.z * b4.z; acc[2][3] += a4.z * b4.w;
                acc[3][0] += a4.w * b4.x; acc[3][1] += a4.w * b4.y; acc[3][2] += a4.w * b4.z; acc[3][3] += a4.w * b4.w;
            }
        }
        float bs[4];
        #pragma unroll
        for (int j = 0; j < 4; ++j) {
            int n = n0 + tx * 4 + j;
            bs[j] = (n < 1600) ? ba1[n] : 0.f;
        }
        #pragma unroll
        for (int i = 0; i < 4; ++i) {
            int tr = t0 + ty * 4 + i;
            float4 o;
            o.x = acc[i][0] + bs[0]; o.y = acc[i][1] + bs[1];
            o.z = acc[i][2] + bs[2]; o.w = acc[i][3] + bs[3];
            *(float4*)(PQ + (size_t)tr * 3200 + n0 + tx * 4) = o;
        }
    }
}

// ---------------- persistent distributed LSTM (exact R4 version, 50 blocks/dir) ----------------
#define LSTM_G 50
__global__ __launch_bounds__(256)
void lstm_kernel(const float* __restrict__ Whh,   // (2,1600,400)
                 const float* __restrict__ h0,    // (4,400)
                 const float* __restrict__ c0,    // (4,400)
                 int hc_base,
                 const float* __restrict__ xg,    // (256,3200): [t][d*1600 + gaterow]
                 u64* __restrict__ hist,          // (2,256,400)
                 u32 tag_base) {
    const int T = 256;
    int bid = blockIdx.x;
    int d  = bid / LSTM_G;
    int wg = bid % LSTM_G;
    int a8 = wg * 8;
    int tid = threadIdx.x;
    int w = tid >> 6, lane = tid & 63;
    int c = lane & 7, r = lane >> 3;
    int gate = r >> 1, jj = r & 1;
    int gr = gate * 400 + a8 + 2 * w + jj;

    __shared__ float hbuf[2][416];

    float4 wv[13];
    const float* wrow = Whh + (size_t)d * 640000 + (size_t)gr * 400;
    #pragma unroll
    for (int i = 0; i < 13; ++i) {
        int k = 4 * (c + 8 * i);
        wv[i] = (k + 3 < 400) ? *(const float4*)(wrow + k) : make_float4(0.f, 0.f, 0.f, 0.f);
    }
    if (tid < 16) { hbuf[0][400 + tid] = 0.f; hbuf[1][400 + tid] = 0.f; }

    float c_state = 0.f;
    if (lane == 0 || lane == 8)
        c_state = c0[(hc_base + d) * 400 + a8 + 2 * w + jj];

    u64* hst = hist + (size_t)d * 102400;
    bool need2 = (tid + 256 < 400);

    for (int t = 0; t < T; ++t) {
        int xt = d ? (T - 1 - t) : t;
        float xgv = xg[(size_t)xt * 3200 + d * 1600 + gr];
        float* hb = hbuf[t & 1];

        if (t == 0) {
            hb[tid] = h0[(hc_base + d) * 400 + tid];
            if (need2) hb[tid + 256] = h0[(hc_base + d) * 400 + tid + 256];
        } else {
            const u64* src = hst + (size_t)(t - 1) * 400;
            u32 want = tag_base + (u32)t;
            bool d1 = false, d2 = !need2;
            while (!(d1 && d2)) {
                u64 v1 = 0, v2 = 0;
                if (!d1) v1 = __hip_atomic_load(&src[tid], __ATOMIC_RELAXED, __HIP_MEMORY_SCOPE_AGENT);
                if (!d2) v2 = __hip_atomic_load(&src[tid + 256], __ATOMIC_RELAXED, __HIP_MEMORY_SCOPE_AGENT);
                if (!d1 && (u32)(v1 >> 32) == want) { hb[tid] = __uint_as_float((u32)v1); d1 = true; }
                if (!d2 && (u32)(v2 >> 32) == want) { hb[tid + 256] = __uint_as_float((u32)v2); d2 = true; }
            }
        }
        __syncthreads();

        const float4* h4 = (const float4*)hb;
        float s = 0.f;
        #pragma unroll
        for (int i = 0; i < 13; ++i) {
            float4 hv = h4[c + 8 * i];
            s += wv[i].x * hv.x + wv[i].y * hv.y + wv[i].z * hv.z + wv[i].w * hv.w;
        }
        s += __shfl_down(s, 4);
        s += __shfl_down(s, 2);
        s += __shfl_down(s, 1);

        float v = 0.f;
        if (c == 0) {
            float tot = s + xgv;
            float arg = (gate == 2) ? 2.f * tot : -tot;
            arg = fminf(fmaxf(arg, -60.f), 60.f);
            float e = __expf(arg);
            v = (gate == 2) ? (e - 1.f) * __frcp_rn(e + 1.f)
                            : __frcp_rn(1.f + e);
        }
        float fv = __shfl(v, lane + 16);
        float gv = __shfl(v, lane + 32);
        float ov = __shfl(v, lane + 48);
        if (lane == 0 || lane == 8) {
            c_state = fv * c_state + v * gv;
            float ec = __expf(fminf(fmaxf(2.f * c_state, -60.f), 60.f));
            float th = (ec - 1.f) * __frcp_rn(ec + 1.f);
            float h = ov * th;
            u64 pk = (((u64)(tag_base + t + 1)) << 32) | (u64)__float_as_uint(h);
            __hip_atomic_store(&hst[(size_t)t * 400 + a8 + 2 * w + jj], pk,
                               __ATOMIC_RELAXED, __HIP_MEMORY_SCOPE_AGENT);
        }
    }
}

// ---------------- arc pairwise scorer (+ borders, folded in) ----------------
__global__ __launch_bounds__(256)
void arc_kernel(const float* __restrict__ PQ,
                const float* __restrict__ Wa2, const float* __restrict__ ba2,
                float* __restrict__ out) {
    int i0 = blockIdx.x * 16, j0 = blockIdx.y * 16;
    int tid = threadIdx.x;
    int ii = tid >> 4, jj = tid & 15;
    __shared__ float Pt[16][65], Qt[16][65];
    __shared__ float W2f[1600];

    if (i0 == 0 && j0 == 0) {   // borders: row 0 (with [0,0]=1) and col 0
        if (tid < 257) out[tid] = (tid == 0) ? 1.0f : 0.0f;
        out[(size_t)(tid + 1) * 257] = 0.0f;
        if (tid == 0) out[0] = 1.0f;
    }
    for (int m = tid; m < 1600; m += 256) W2f[m] = Wa2[m];
    __syncthreads();

    float acc = 0.f;
    int mm = tid & 63, r4 = tid >> 6;
    for (int m0 = 0; m0 < 1600; m0 += 64) {
        #pragma unroll
        for (int rr = r4; rr < 16; rr += 4) {
            Pt[rr][mm] = PQ[(size_t)(i0 + rr) * 3200 + m0 + mm];
            Qt[rr][mm] = PQ[(size_t)(j0 + rr) * 3200 + 1600 + m0 + mm];
        }
        __syncthreads();
        #pragma unroll 8
        for (int m = 0; m < 64; ++m) {
            float s = Pt[ii][m] + Qt[jj][m];
            acc += W2f[m0 + m] * fast_tanh(s);
        }
        __syncthreads();
    }
    float raw = acc + ba2[0];
    int gi = i0 + ii, gj = j0 + jj;
    if (gi == gj) raw = 0.f;
    out[(size_t)(gi + 1) * 257 + (gj + 1)] = raw;
}

// ---------------- label output ----------------
__global__ __launch_bounds__(256)
void label_out_kernel(const float* __restrict__ U, const float* __restrict__ Wl2,
                      const float* __restrict__ bl2, const int* __restrict__ arcs,
                      float* __restrict__ out) {
    int t = blockIdx.x;
    __shared__ float u_l[1600];
    __shared__ float part[4][64];
    for (int m = threadIdx.x; m < 1600; m += 256) u_l[m] = U[(size_t)t * 1600 + m];
    __syncthreads();
    int tid = threadIdx.x;
    int n = tid & 63, p = tid >> 6;
    float acc = 0.f;
    if (n < 40) {
        const float4* wr4 = (const float4*)(Wl2 + (size_t)n * 1600 + p * 400);
        const float*  ub  = u_l + p * 400;
        for (int m = 0; m < 100; ++m) {
            float4 w = wr4[m];
            acc += ub[4*m] * w.x + ub[4*m+1] * w.y + ub[4*m+2] * w.z + ub[4*m+3] * w.w;
        }
    }
    part[p][n] = acc;
    __syncthreads();
    if (tid < 40) {
        float v = part[0][tid] + part[1][tid] + part[2][tid] + part[3][tid] + bl2[tid];
        if (arcs[1 + t] == 0) v = 0.f;
        out[(size_t)t * 40 + tid] = v;
    }
}

// ---------------- launch ----------------
extern "C" void kernel_launch(void* const* d_in, const int* in_sizes, int n_in,
                              void* d_out, int out_size, void* d_ws, size_t ws_size,
                              hipStream_t stream) {
    const int*   words = (const int*)d_in[0];
    const int*   tags  = (const int*)d_in[1];
    const int*   arcs  = (const int*)d_in[2];
    const float* h0    = (const float*)d_in[3];
    const float* c0    = (const float*)d_in[4];
    const float* wemb  = (const float*)d_in[5];
    const float* temb  = (const float*)d_in[6];
    const float* Wih0  = (const float*)d_in[7];
    const float* Whh0  = (const float*)d_in[8];
    const float* bih0  = (const float*)d_in[9];
    const float* bhh0  = (const float*)d_in[10];
    const float* Wih1  = (const float*)d_in[11];
    const float* Whh1  = (const float*)d_in[12];
    const float* bih1  = (const float*)d_in[13];
    const float* bhh1  = (const float*)d_in[14];
    const float* Wa1   = (const float*)d_in[15];
    const float* ba1   = (const float*)d_in[16];
    const float* Wa2   = (const float*)d_in[17];
    const float* ba2   = (const float*)d_in[18];
    const float* Wl1   = (const float*)d_in[19];
    const float* bl1   = (const float*)d_in[20];
    const float* Wl2   = (const float*)d_in[21];
    const float* bl2   = (const float*)d_in[22];
    float* out = (float*)d_out;

    char* ws = (char*)d_ws;
    float* xg   = (float*)(ws + OF_XG);
    u64*   hist = (u64*)  (ws + OF_H);
    float* PQ   = (float*)(ws + OF_PQ);
    float* U    = (float*)(ws + OF_U);

    gemm_embed_kernel<<<dim3(4, 50), 256, 0, stream>>>(words, tags, wemb, temb, Wih0, bih0, bhh0, xg);
    lstm_kernel<<<2 * LSTM_G, 256, 0, stream>>>(Whh0, h0, c0, 0, xg, hist, 0u);
    gemm_hist_kernel<<<dim3(4, 50), 256, 0, stream>>>(hist, nullptr, Wih1, 800, 0, bih1, bhh1, xg, 3200, 800, 0);
    lstm_kernel<<<2 * LSTM_G, 256, 0, stream>>>(Whh1, h0, c0, 2, xg, hist, 256u);
    pq_u_kernel<<<dim3(4, 75), 256, 0, stream>>>(hist, arcs, Wa1, ba1, Wl1, bl1, PQ, U);
    arc_kernel<<<dim3(16, 16), 256, 0, stream>>>(PQ, Wa2, ba2, out);
    label_out_kernel<<<256, 256, 0, stream>>>(U, Wl2, bl2, arcs, out + 66049);
}